// Round 12
// baseline (378.807 us; speedup 1.0000x reference)
//
#include <hip/hip_runtime.h>

#define NB 64
#define NDIM 512
#define NNE (NDIM * NDIM)      // 262144
#define NR 40
#define NL 20
#define SUBS 16                // blocks per batch
#define IT 16                  // float4 iters per thread (64 elems)

// ws layout (floats): per main block, MAIN_STRIDE=256 floats:
//   [w*10 .. w*10+9]  (w=0..3): wave scalar partials
//       0..3=tat, 4=dmd_time, 5=unserved, 6=tot_dem, 7=n_disc, 8=n_edges, 9=max_drive
//   [40 + g*40 + j] (g=0..3, j=0..39): rider partials (row-group g, bin j)
#define MAIN_STRIDE 256
#define OUT_RIDERS 64
#define OUT_TAT (64 + NB * NR)
#define OUT_TRT (64 + NB * NR + NB * 4)

// bcol = bins + tid (column-major): bin j at bcol[j*256]. Bank = tid%32 for
// every access (id-independent); each thread owns its column -> no
// same-address collisions. atomicAdd (result unused) -> single no-return
// ds_add_f32: 4 DS instrs/element instead of 8, no read->write dependency.
__device__ __forceinline__ void procE(float d, float ttv, float dtv, int ntv, int hv,
                                      int i0, int i1, int i2, int i3,
                                      float acc[10], float* __restrict__ bcol)
{
    const bool np_ = (hv == 0);
    const int nte = np_ ? 3 : ntv;
    acc[0] += (nte == 0) ? d : 0.0f;
    acc[1] += (nte == 1) ? d : 0.0f;
    acc[2] += (nte == 2) ? d : 0.0f;
    acc[3] += (nte > 2) ? d : 0.0f;
    acc[4] += np_ ? 0.0f : d * ttv;
    acc[5] += np_ ? d : 0.0f;
    acc[6] += d;
    const bool pos = d > 0.0f;
    acc[7] += (np_ && pos) ? 1.0f : 0.0f;
    acc[8] += pos ? 1.0f : 0.0f;
    acc[9] = fmaxf(acc[9], dtv);

    // invalid (-1) -> clamp to bin 39 with weight 0 (harmless fused RMW)
    const unsigned u0 = (unsigned)i0, u1 = (unsigned)i1,
                   u2 = (unsigned)i2, u3 = (unsigned)i3;
    const unsigned b0 = min(u0, (unsigned)(NR - 1));
    const unsigned b1 = min(u1, (unsigned)(NR - 1));
    const unsigned b2 = min(u2, (unsigned)(NR - 1));
    const unsigned b3 = min(u3, (unsigned)(NR - 1));
    const float w0 = (u0 < NR) ? d : 0.0f;
    const float w1 = (u1 < NR) ? d : 0.0f;
    const float w2 = (u2 < NR) ? d : 0.0f;
    const float w3 = (u3 < NR) ? d : 0.0f;
    atomicAdd(bcol + b0 * 256, w0);
    atomicAdd(bcol + b1 * 256, w1);
    atomicAdd(bcol + b2 * 256, w2);
    atomicAdd(bcol + b3 * 256, w3);
}

template<bool BYTE>
__device__ __forceinline__ void mloop(
    const float* __restrict__ pd, const float* __restrict__ pt,
    const float* __restrict__ pdr, const int* __restrict__ pn,
    const void* __restrict__ ph, const int* __restrict__ pr,
    float acc[10], float* __restrict__ bcol)
{
#pragma unroll 2
    for (int it = 0; it < IT; ++it) {
        const int o = it * 1024;
        const float4 dem = *(const float4*)(pd + o);
        const float4 tt  = *(const float4*)(pt + o);
        const float4 dt  = *(const float4*)(pdr + o);
        const int4   nt  = *(const int4*)(pn + o);
        const int4 r0 = *(const int4*)(pr + o * 4);
        const int4 r1 = *(const int4*)(pr + o * 4 + 4);
        const int4 r2 = *(const int4*)(pr + o * 4 + 8);
        const int4 r3 = *(const int4*)(pr + o * 4 + 12);
        int h0, h1, h2, h3;
        if (BYTE) {
            const uchar4 hb = *(const uchar4*)((const unsigned char*)ph + o);
            h0 = hb.x; h1 = hb.y; h2 = hb.z; h3 = hb.w;
        } else {
            const int4 hw = *(const int4*)((const int*)ph + o);
            h0 = hw.x; h1 = hw.y; h2 = hw.z; h3 = hw.w;
        }
        procE(dem.x, tt.x, dt.x, nt.x, h0, r0.x, r0.y, r0.z, r0.w, acc, bcol);
        procE(dem.y, tt.y, dt.y, nt.y, h1, r1.x, r1.y, r1.z, r1.w, acc, bcol);
        procE(dem.z, tt.z, dt.z, nt.z, h2, r2.x, r2.y, r2.z, r2.w, acc, bcol);
        procE(dem.w, tt.w, dt.w, nt.w, h3, r3.x, r3.y, r3.z, r3.w, acc, bcol);
    }
}

__global__ __launch_bounds__(256, 4) void main_kernel(
    const float* __restrict__ demand,
    const float* __restrict__ transit,
    const float* __restrict__ drive,
    const int* __restrict__ ntr,
    const unsigned char* __restrict__ hp_raw,
    const int* __restrict__ rseq,
    float* __restrict__ ws)
{
    __shared__ float bins[NR * 256];   // exactly 40 KB, column-major
    const int tid = threadIdx.x;
    const int wave = tid >> 6, lane = tid & 63;
    float* __restrict__ bcol = bins + tid;
#pragma unroll
    for (int j = 0; j < NR; ++j) bcol[j * 256] = 0.0f;   // own column: no barrier

    // in-wave has_path layout detection from the first 1 KB (in-bounds for
    // both layouts): byte layout packs 4 bools/word -> some word > 1 w.p. ~1.
    const unsigned wdet = ((const unsigned*)hp_raw)[tid];
    const bool isByte = __any(wdet > 1u);

    const int b = blockIdx.x >> 4, sub = blockIdx.x & 15;
    const size_t e0 = (size_t)b * NNE + (size_t)sub * (NNE / SUBS) + (size_t)tid * 4;

    float acc[10] = {0, 0, 0, 0, 0, 0, 0, 0, 0, 0};
    if (isByte)
        mloop<true>(demand + e0, transit + e0, drive + e0, ntr + e0,
                    hp_raw + e0, rseq + e0 * 4, acc, bcol);
    else
        mloop<false>(demand + e0, transit + e0, drive + e0, ntr + e0,
                     ((const int*)hp_raw) + e0, rseq + e0 * 4, acc, bcol);

    // wave reduction: 9 sums + 1 max; lane0 stores partials straight to ws
#pragma unroll
    for (int o = 32; o > 0; o >>= 1) {
#pragma unroll
        for (int v = 0; v < 9; ++v) acc[v] += __shfl_down(acc[v], o);
        acc[9] = fmaxf(acc[9], __shfl_down(acc[9], o));
    }
    float* part = ws + (size_t)blockIdx.x * MAIN_STRIDE;
    if (lane == 0) {
#pragma unroll
        for (int v = 0; v < 10; ++v) part[wave * 10 + v] = acc[v];
    }
    __syncthreads();   // bins complete

    // rider tail: 160 threads, thread (g,j) sums 64 columns of bin j
    if (tid < 4 * NR) {
        const int g = tid / NR, j = tid - g * NR;
        float s = 0.0f;
#pragma unroll 8
        for (int r = g * 64; r < g * 64 + 64; ++r) s += bins[j * 256 + r];
        part[40 + g * NR + j] = s;
    }
}

// ---------------- finalize (route legs fused in) ----------------
__global__ __launch_bounds__(64) void final_kernel(
    const float* __restrict__ ws,
    const int* __restrict__ routes,
    const float* __restrict__ drive,
    float* __restrict__ out)
{
    __shared__ float fin[50];
    __shared__ float rt3[3];
    const int b = blockIdx.x;
    const int v = threadIdx.x;

    // --- route leg times ---
    float t = 0.0f, used = 0.0f, oob = 0.0f;
    if (v < NR) {
        const int* rt = routes + (b * NR + v) * NL;
        int rv[NL];
        int len = 0;
#pragma unroll
        for (int l = 0; l < NL; ++l) { rv[l] = rt[l]; len += (rv[l] > -1) ? 1 : 0; }
        const float* D = drive + (size_t)b * NNE;
#pragma unroll
        for (int l = 0; l < NL - 1; ++l) {
            int f = rv[l], to = rv[l + 1];
            if (f >= 0 && to >= 0)
                t += D[f * NDIM + to] + D[to * NDIM + f] + 120.0f;
        }
        used = (len > 0) ? 1.0f : 0.0f;
        int delta = 2 - len;
        oob = (len > 0 && delta > 0) ? (float)delta : 0.0f;
    }
#pragma unroll
    for (int o = 32; o > 0; o >>= 1) {
        t += __shfl_down(t, o);
        used += __shfl_down(used, o);
        oob += __shfl_down(oob, o);
    }
    if (v == 0) { rt3[0] = t; rt3[1] = used; rt3[2] = oob; }

    // --- gather partials: riders (v<40), scalars (v in 40..49) ---
    const float* base = ws + (size_t)b * SUBS * MAIN_STRIDE;
    if (v < NR) {
        float s = 0.0f;
#pragma unroll 4
        for (int i = 0; i < SUBS * 4; ++i)
            s += base[(i >> 2) * MAIN_STRIDE + 40 + (i & 3) * NR + v];
        fin[v] = s;
    } else if (v < 50) {
        const int k = v - 40;
        if (k == 9) {
            float m = 0.0f;
#pragma unroll 4
            for (int i = 0; i < SUBS * 4; ++i)
                m = fmaxf(m, base[(i >> 2) * MAIN_STRIDE + (i & 3) * 10 + 9]);
            fin[v] = m;
        } else {
            float s = 0.0f;
#pragma unroll 4
            for (int i = 0; i < SUBS * 4; ++i)
                s += base[(i >> 2) * MAIN_STRIDE + (i & 3) * 10 + k];
            fin[v] = s;
        }
    }
    __syncthreads();

    if (v == 0) {
        const float trt = rt3[0], nru = rt3[1], noob = rt3[2];
        const float dmdt = fin[44], uns = fin[45], tdem = fin[46];
        const float ndisc = fin[47], nedge = fin[48], tn = fin[49];
        const float served = tdem - uns;
        const float cost = 0.5f * ((dmdt / (served + 1e-6f)) / tn)
                         + 0.5f * (trt / (tn * nru + 1e-6f))
                         + 5.0f * (ndisc / nedge + noob / (nru * 2.0f + 1e-6f));
        out[b] = cost;
        out[OUT_TRT + b] = trt;
    }
    if (v < NR) out[OUT_RIDERS + b * NR + v] = fin[v];
    if (v >= 40 && v < 44) out[OUT_TAT + b * 4 + (v - 40)] = fin[v];
}

extern "C" void kernel_launch(void* const* d_in, const int* in_sizes, int n_in,
                              void* d_out, int out_size, void* d_ws, size_t ws_size,
                              hipStream_t stream) {
    const float* demand  = (const float*)d_in[0];
    const float* drive   = (const float*)d_in[1];
    const float* transit = (const float*)d_in[2];
    const unsigned char* hp = (const unsigned char*)d_in[3];
    const int* ntr    = (const int*)d_in[4];
    const int* routes = (const int*)d_in[5];
    const int* rseq   = (const int*)d_in[6];
    float* out = (float*)d_out;
    float* ws  = (float*)d_ws;

    main_kernel<<<NB * SUBS, 256, 0, stream>>>(demand, transit, drive, ntr, hp, rseq, ws);
    final_kernel<<<NB, 64, 0, stream>>>(ws, routes, drive, out);
}

// Round 13
// 127.632 us; speedup vs baseline: 2.9680x; 2.9680x over previous
//
#include <hip/hip_runtime.h>

#define NB 64
#define NDIM 512
#define NNE (NDIM * NDIM)      // 262144
#define NR 40
#define NL 20
#define SUBS 16                // blocks per batch
#define IT 16                  // float4 iters per thread (64 elems)
#define BINS 41                // 40 real + 1 dummy for invalid ids

// ws layout (floats): per main block, MAIN_STRIDE=64 floats:
//   [0..3]=tat, 4=dmd_time, 5=unserved, 6=tot_dem, 7=n_disc, 8=n_edges,
//   9=max_drive, [10..49]=riders
#define MAIN_STRIDE 64
#define OUT_RIDERS 64
#define OUT_TAT (64 + NB * NR)
#define OUT_TRT (64 + NB * NR + NB * 4)

// ---------------- fused main: scalars + max + rider bins (batched LDS RMW) ----
template<bool BYTE>
__device__ __forceinline__ void procE(float d, float ttv, float dtv, int ntv, int hv,
                                      int i0, int i1, int i2, int i3,
                                      float acc[10], float* __restrict__ myrow)
{
    const bool np_ = (hv == 0);
    const int nte = np_ ? 3 : ntv;
    acc[0] += (nte == 0) ? d : 0.0f;
    acc[1] += (nte == 1) ? d : 0.0f;
    acc[2] += (nte == 2) ? d : 0.0f;
    acc[3] += (nte > 2) ? d : 0.0f;
    acc[4] += np_ ? 0.0f : d * ttv;
    acc[5] += np_ ? d : 0.0f;
    acc[6] += d;
    const bool pos = d > 0.0f;
    acc[7] += (np_ && pos) ? 1.0f : 0.0f;
    acc[8] += pos ? 1.0f : 0.0f;
    acc[9] = fmaxf(acc[9], dtv);

    // batched rider RMW: 4 reads, dup-resolve in regs, 4 writes.
    // invalid (-1) -> 0xFFFFFFFF -> min -> dummy bin 40 (discarded).
    // addend_k = d * (1 + #{j<k : bj == bk}); in-order writes -> last dup
    // carries the full sum.
    const unsigned b0 = min((unsigned)i0, (unsigned)(BINS - 1));
    const unsigned b1 = min((unsigned)i1, (unsigned)(BINS - 1));
    const unsigned b2 = min((unsigned)i2, (unsigned)(BINS - 1));
    const unsigned b3 = min((unsigned)i3, (unsigned)(BINS - 1));
    const float a0 = d;
    const float a1 = d * (1.0f + (b1 == b0));
    const float a2 = d * (1.0f + (b2 == b0) + (b2 == b1));
    const float a3 = d * (1.0f + (b3 == b0) + (b3 == b1) + (b3 == b2));
    const float v0 = myrow[b0];
    const float v1 = myrow[b1];
    const float v2 = myrow[b2];
    const float v3 = myrow[b3];
    myrow[b0] = v0 + a0;
    myrow[b1] = v1 + a1;
    myrow[b2] = v2 + a2;
    myrow[b3] = v3 + a3;
}

template<bool BYTE>
__device__ __forceinline__ void mloop(
    const float* __restrict__ pd, const float* __restrict__ pt,
    const float* __restrict__ pdr, const int* __restrict__ pn,
    const void* __restrict__ ph, const int* __restrict__ pr,
    float acc[10], float* __restrict__ myrow)
{
#pragma unroll 2
    for (int it = 0; it < IT; ++it) {
        const int o = it * 1024;
        const float4 dem = *(const float4*)(pd + o);
        const float4 tt  = *(const float4*)(pt + o);
        const float4 dt  = *(const float4*)(pdr + o);
        const int4   nt  = *(const int4*)(pn + o);
        const int4 r0 = *(const int4*)(pr + o * 4);
        const int4 r1 = *(const int4*)(pr + o * 4 + 4);
        const int4 r2 = *(const int4*)(pr + o * 4 + 8);
        const int4 r3 = *(const int4*)(pr + o * 4 + 12);
        int h0, h1, h2, h3;
        if (BYTE) {
            const uchar4 hb = *(const uchar4*)((const unsigned char*)ph + o);
            h0 = hb.x; h1 = hb.y; h2 = hb.z; h3 = hb.w;
        } else {
            const int4 hw = *(const int4*)((const int*)ph + o);
            h0 = hw.x; h1 = hw.y; h2 = hw.z; h3 = hw.w;
        }
        procE<BYTE>(dem.x, tt.x, dt.x, nt.x, h0, r0.x, r0.y, r0.z, r0.w, acc, myrow);
        procE<BYTE>(dem.y, tt.y, dt.y, nt.y, h1, r1.x, r1.y, r1.z, r1.w, acc, myrow);
        procE<BYTE>(dem.z, tt.z, dt.z, nt.z, h2, r2.x, r2.y, r2.z, r2.w, acc, myrow);
        procE<BYTE>(dem.w, tt.w, dt.w, nt.w, h3, r3.x, r3.y, r3.z, r3.w, acc, myrow);
    }
}

__global__ __launch_bounds__(256, 3) void main_kernel(
    const float* __restrict__ demand,
    const float* __restrict__ transit,
    const float* __restrict__ drive,
    const int* __restrict__ ntr,
    const unsigned char* __restrict__ hp_raw,
    const int* __restrict__ rseq,
    float* __restrict__ ws)
{
    __shared__ float bins[256 * BINS];   // 42 KB; one private 41-bin row per thread
    __shared__ float red[4][10];
    __shared__ float red2[4][NR];
    const int tid = threadIdx.x;
    const int wave = tid >> 6, lane = tid & 63;
    float* __restrict__ myrow = bins + tid * BINS;
#pragma unroll
    for (int i = 0; i < BINS; ++i) myrow[i] = 0.0f;   // private row: no barrier

    // in-wave has_path layout detection from the first 1 KB (in-bounds for
    // both layouts): byte layout packs 4 bools/word -> some word > 1 w.p. ~1.
    const unsigned wdet = ((const unsigned*)hp_raw)[tid];
    const bool isByte = __any(wdet > 1u);

    const int b = blockIdx.x >> 4, sub = blockIdx.x & 15;
    const size_t e0 = (size_t)b * NNE + (size_t)sub * (NNE / SUBS) + (size_t)tid * 4;

    float acc[10] = {0, 0, 0, 0, 0, 0, 0, 0, 0, 0};
    if (isByte)
        mloop<true>(demand + e0, transit + e0, drive + e0, ntr + e0,
                    hp_raw + e0, rseq + e0 * 4, acc, myrow);
    else
        mloop<false>(demand + e0, transit + e0, drive + e0, ntr + e0,
                     ((const int*)hp_raw) + e0, rseq + e0 * 4, acc, myrow);

    // wave reduction: 9 sums + 1 max
#pragma unroll
    for (int o = 32; o > 0; o >>= 1) {
#pragma unroll
        for (int v = 0; v < 9; ++v) acc[v] += __shfl_down(acc[v], o);
        acc[9] = fmaxf(acc[9], __shfl_down(acc[9], o));
    }
    if (lane == 0) {
#pragma unroll
        for (int v = 0; v < 10; ++v) red[wave][v] = acc[v];
    }
    __syncthreads();   // red + bins complete

    float* part = ws + (size_t)blockIdx.x * MAIN_STRIDE;
    if (tid < 10) {
        if (tid == 9)
            part[9] = fmaxf(fmaxf(red[0][9], red[1][9]), fmaxf(red[2][9], red[3][9]));
        else
            part[tid] = red[0][tid] + red[1][tid] + red[2][tid] + red[3][tid];
    }

    // 4-way parallel rider tail: 160 threads, each sums 64 rows of one bin
    if (tid < 4 * NR) {
        const int g = tid / NR, j = tid - g * NR;
        float s = 0.0f;
#pragma unroll 8
        for (int r = g * 64; r < g * 64 + 64; ++r) s += bins[r * BINS + j];
        red2[g][j] = s;
    }
    __syncthreads();
    if (tid < NR)
        part[10 + tid] = red2[0][tid] + red2[1][tid] + red2[2][tid] + red2[3][tid];
}

// ---------------- finalize (route legs fused in) ----------------
__global__ __launch_bounds__(64) void final_kernel(
    const float* __restrict__ ws,
    const int* __restrict__ routes,
    const float* __restrict__ drive,
    float* __restrict__ out)
{
    __shared__ float fin[50];
    __shared__ float rt3[3];
    const int b = blockIdx.x;
    const int v = threadIdx.x;

    // --- route leg times ---
    float t = 0.0f, used = 0.0f, oob = 0.0f;
    if (v < NR) {
        const int* rt = routes + (b * NR + v) * NL;
        int rv[NL];
        int len = 0;
#pragma unroll
        for (int l = 0; l < NL; ++l) { rv[l] = rt[l]; len += (rv[l] > -1) ? 1 : 0; }
        const float* D = drive + (size_t)b * NNE;
#pragma unroll
        for (int l = 0; l < NL - 1; ++l) {
            int f = rv[l], to = rv[l + 1];
            if (f >= 0 && to >= 0)
                t += D[f * NDIM + to] + D[to * NDIM + f] + 120.0f;
        }
        used = (len > 0) ? 1.0f : 0.0f;
        int delta = 2 - len;
        oob = (len > 0 && delta > 0) ? (float)delta : 0.0f;
    }
#pragma unroll
    for (int o = 32; o > 0; o >>= 1) {
        t += __shfl_down(t, o);
        used += __shfl_down(used, o);
        oob += __shfl_down(oob, o);
    }
    if (v == 0) { rt3[0] = t; rt3[1] = used; rt3[2] = oob; }

    // --- gather per-block partials ---
    const float* base = ws + (size_t)b * SUBS * MAIN_STRIDE;
    if (v < 50) {
        float a = base[v];
#pragma unroll
        for (int s = 1; s < SUBS; ++s) {
            const float x = base[(size_t)s * MAIN_STRIDE + v];
            a = (v == 9) ? fmaxf(a, x) : (a + x);
        }
        fin[v] = a;
    }
    __syncthreads();

    if (v == 0) {
        const float trt = rt3[0], nru = rt3[1], noob = rt3[2];
        const float dmdt = fin[4], uns = fin[5], tdem = fin[6];
        const float ndisc = fin[7], nedge = fin[8], tn = fin[9];
        const float served = tdem - uns;
        const float cost = 0.5f * ((dmdt / (served + 1e-6f)) / tn)
                         + 0.5f * (trt / (tn * nru + 1e-6f))
                         + 5.0f * (ndisc / nedge + noob / (nru * 2.0f + 1e-6f));
        out[b] = cost;
        out[OUT_TRT + b] = trt;
    }
    if (v >= 10 && v < 50) out[OUT_RIDERS + b * NR + (v - 10)] = fin[v];
    if (v < 4) out[OUT_TAT + b * 4 + v] = fin[v];
}

extern "C" void kernel_launch(void* const* d_in, const int* in_sizes, int n_in,
                              void* d_out, int out_size, void* d_ws, size_t ws_size,
                              hipStream_t stream) {
    const float* demand  = (const float*)d_in[0];
    const float* drive   = (const float*)d_in[1];
    const float* transit = (const float*)d_in[2];
    const unsigned char* hp = (const unsigned char*)d_in[3];
    const int* ntr    = (const int*)d_in[4];
    const int* routes = (const int*)d_in[5];
    const int* rseq   = (const int*)d_in[6];
    float* out = (float*)d_out;
    float* ws  = (float*)d_ws;

    main_kernel<<<NB * SUBS, 256, 0, stream>>>(demand, transit, drive, ntr, hp, rseq, ws);
    final_kernel<<<NB, 64, 0, stream>>>(ws, routes, drive, out);
}